// Round 14
// baseline (4485.751 us; speedup 1.0000x reference)
//
#include <hip/hip_runtime.h>

// CGIterator: N=50000 nodes, K=128, I=4 chained CG iterations, fp32.
// Round-14 = round-13 (packed 16B weight quads in d_ws, 128 thr, NB=2, TN=2,
// LDS 30.2KB, launch_bounds(128,4) -> VGPR 116 no-spill) + scheduler-driven
// load hoisting:
//  (a) #pragma unroll 2 on both linear loops: two independent load/FMA batches
//      per body lets the COMPILER hoist next-batch loads above current FMAs
//      within its own 128-reg budget (manual dbuf spilled every time: r8/r12).
//  (b) batch-0 peel: lin_in's first 6 quad loads issue BEFORE the post-RMS
//      barrier; lin_out's first 6 issue under the s_tp writes + barrier.
// Same bytes, same FMA order per accumulator -> bit-identical output.

#define NNODES 50000
#define KCH 128          // K
#define PCH 256          // 2K
#define NITER 4
#define NB 2             // nodes per block
#define NTHR 128

#define PW_QUADS (12 * 64 * 128)     // g(12) x k2(64) x t(128), 16B each
#define PV_QUADS (12 * 128 * 64)     // g(12) x p2(128) x ln(64), 16B each
#define PACK_BYTES ((size_t)(PW_QUADS + PV_QUADS) * 16)

// ---- packed-quad load/step macros (buffer name parameterized) ----
#define LOADWQ(buf, kb) do { \
    const int k2_ = (kb) >> 1; \
    buf[0][0] = *(const float4*)&P0[(size_t)(k2_    ) * 512]; \
    buf[0][1] = *(const float4*)&P0[(size_t)(k2_ + 1) * 512]; \
    buf[1][0] = *(const float4*)&P1[(size_t)(k2_    ) * 512]; \
    buf[1][1] = *(const float4*)&P1[(size_t)(k2_ + 1) * 512]; \
    buf[2][0] = *(const float4*)&P2[(size_t)(k2_    ) * 512]; \
    buf[2][1] = *(const float4*)&P2[(size_t)(k2_ + 1) * 512]; \
} while (0)

#define INSTEPQ(buf, kb) do { \
    _Pragma("unroll") \
    for (int n = 0; n < NB; ++n) { \
        _Pragma("unroll") \
        for (int m = 0; m < 9; ++m) { \
            const int lm = (m == 0) ? 0 : ((m < 4) ? 1 : 2); \
            const float4 h4 = *(const float4*)&s_h[n][m][(kb)]; \
            float a = hcA[n][m], b = hcB[n][m]; \
            a = fmaf(h4.x, buf[lm][0].x, a); \
            b = fmaf(h4.x, buf[lm][0].y, b); \
            a = fmaf(h4.y, buf[lm][0].z, a); \
            b = fmaf(h4.y, buf[lm][0].w, b); \
            a = fmaf(h4.z, buf[lm][1].x, a); \
            b = fmaf(h4.z, buf[lm][1].y, b); \
            a = fmaf(h4.w, buf[lm][1].z, a); \
            b = fmaf(h4.w, buf[lm][1].w, b); \
            hcA[n][m] = a; hcB[n][m] = b; \
        } \
    } \
} while (0)

#define LOADVQ(buf, pb) do { \
    const int p2_ = (pb0 + (pb)) >> 1; \
    buf[0][0] = *(const float4*)&Q0[(size_t)(p2_    ) * 256]; \
    buf[0][1] = *(const float4*)&Q0[(size_t)(p2_ + 1) * 256]; \
    buf[1][0] = *(const float4*)&Q1[(size_t)(p2_    ) * 256]; \
    buf[1][1] = *(const float4*)&Q1[(size_t)(p2_ + 1) * 256]; \
    buf[2][0] = *(const float4*)&Q2[(size_t)(p2_    ) * 256]; \
    buf[2][1] = *(const float4*)&Q2[(size_t)(p2_ + 1) * 256]; \
} while (0)

#define OUTSTEPQ(buf, pb) do { \
    _Pragma("unroll") \
    for (int n = 0; n < NB; ++n) { \
        _Pragma("unroll") \
        for (int m = 0; m < 9; ++m) { \
            const int lm = (m == 0) ? 0 : ((m < 4) ? 1 : 2); \
            const float4 t4 = *(const float4*)&s_tp[n][m][pb0 + (pb)]; \
            float a = oaA[n][m], b = oaB[n][m]; \
            a = fmaf(t4.x, buf[lm][0].x, a); \
            b = fmaf(t4.x, buf[lm][0].y, b); \
            a = fmaf(t4.y, buf[lm][0].z, a); \
            b = fmaf(t4.y, buf[lm][0].w, b); \
            a = fmaf(t4.z, buf[lm][1].x, a); \
            b = fmaf(t4.z, buf[lm][1].y, b); \
            a = fmaf(t4.w, buf[lm][1].z, a); \
            b = fmaf(t4.w, buf[lm][1].w, b); \
            oaA[n][m] = a; oaB[n][m] = b; \
        } \
    } \
} while (0)

// ---------------- pack kernel (once per launch, ~6 MB of HBM traffic) ----
__global__ __launch_bounds__(256)
void pack_weights(const float* __restrict__ W_in, const float* __restrict__ W_out,
                  float* __restrict__ PW, float* __restrict__ PV)
{
    const int idx = blockIdx.x * 256 + threadIdx.x;
    if (idx < PW_QUADS) {
        const int t  = idx & 127;
        const int k2 = (idx >> 7) & 63;
        const int g  = idx >> 13;
        const float* src = W_in + (size_t)g * KCH * PCH;
        float4 v;
        v.x = src[(2 * k2    ) * PCH + 2 * t    ];
        v.y = src[(2 * k2    ) * PCH + 2 * t + 1];
        v.z = src[(2 * k2 + 1) * PCH + 2 * t    ];
        v.w = src[(2 * k2 + 1) * PCH + 2 * t + 1];
        *(float4*)&PW[(size_t)idx * 4] = v;
    } else if (idx < PW_QUADS + PV_QUADS) {
        const int j  = idx - PW_QUADS;
        const int ln = j & 63;
        const int p2 = (j >> 6) & 127;
        const int g  = j >> 13;
        const float* src = W_out + (size_t)g * PCH * KCH;
        float4 v;
        v.x = src[(2 * p2    ) * KCH + 2 * ln    ];
        v.y = src[(2 * p2    ) * KCH + 2 * ln + 1];
        v.z = src[(2 * p2 + 1) * KCH + 2 * ln    ];
        v.w = src[(2 * p2 + 1) * KCH + 2 * ln + 1];
        *(float4*)&PV[(size_t)j * 4] = v;
    }
}

// ---------------- main kernel (packed weights) ---------------------------
__global__ __launch_bounds__(NTHR, 4)
void cg_fused_pk(const float* __restrict__ f0,
                 const float* __restrict__ f1,
                 const float* __restrict__ f2,
                 const float* __restrict__ Uin,
                 const float* __restrict__ gamma,
                 const float* __restrict__ PW,
                 const float* __restrict__ PV,
                 float* __restrict__ out)
{
    __shared__ float sUp[45][12];                 // 2.1 KB
    __shared__ float s_h[NB][9][KCH];             // 9.2 KB
    __shared__ float s_tp[NB][9][PCH];            // 18.4 KB; exchange overlay
    float (*s_part)[18][KCH] = reinterpret_cast<float (*)[18][KCH]>(&s_tp[0][0][0]);

    const int tid = threadIdx.x;      // 0..127
    const int w   = tid >> 6;         // wave: 0 or 1 (uniform)
    const int ln  = tid & 63;
    const int kk  = tid;
    const int node0 = blockIdx.x * NB;

    for (int idx = tid; idx < 45 * 12; idx += NTHR) {
        const int ab = idx / 12;
        const int c  = idx % 12;
        int a = 0, r = ab;
        while (r >= 9 - a) { r -= 9 - a; ++a; }
        const int b = a + r;
        float v = 0.0f;
        if (c < 9) {
            v = Uin[(a * 9 + b) * 9 + c];
            if (a != b) v += Uin[(b * 9 + a) * 9 + c];
        }
        sUp[ab][c] = v;
    }

    float f[NB][9];
    #pragma unroll
    for (int n = 0; n < NB; ++n) {
        const int ng = node0 + n;
        f[n][0] = f0[ng * KCH + kk];
        #pragma unroll
        for (int m = 0; m < 3; ++m) f[n][1 + m] = f1[(ng * 3 + m) * KCH + kk];
        #pragma unroll
        for (int m = 0; m < 5; ++m) f[n][4 + m] = f2[(ng * 5 + m) * KCH + kk];
    }

    for (int it = 0; it < NITER; ++it) {
        const float* P0 = PW + (size_t)(it * 3 + 0) * 64 * 128 * 4 + 4 * tid;
        const float* P1 = PW + (size_t)(it * 3 + 1) * 64 * 128 * 4 + 4 * tid;
        const float* P2 = PW + (size_t)(it * 3 + 2) * 64 * 128 * 4 + 4 * tid;

        // ---------- step 1: RMS norm -> s_h ----------
        {
            const float g0 = gamma[(it * 3 + 0) * KCH + kk];
            const float g1 = gamma[(it * 3 + 1) * KCH + kk];
            const float g2 = gamma[(it * 3 + 2) * KCH + kk];
            #pragma unroll
            for (int n = 0; n < NB; ++n) {
                const float s0 = f[n][0] * f[n][0];
                const float s1 = f[n][1] * f[n][1] + f[n][2] * f[n][2] + f[n][3] * f[n][3];
                const float s2 = f[n][4] * f[n][4] + f[n][5] * f[n][5] + f[n][6] * f[n][6]
                               + f[n][7] * f[n][7] + f[n][8] * f[n][8];
                const float r0 = rsqrtf(s0 + 1e-6f) * g0;
                const float r1 = rsqrtf(s1 * (1.0f / 3.0f) + 1e-6f) * g1;
                const float r2 = rsqrtf(s2 * (1.0f / 5.0f) + 1e-6f) * g2;
                s_h[n][0][kk] = f[n][0] * r0;
                s_h[n][1][kk] = f[n][1] * r1;
                s_h[n][2][kk] = f[n][2] * r1;
                s_h[n][3][kk] = f[n][3] * r1;
                s_h[n][4][kk] = f[n][4] * r2;
                s_h[n][5][kk] = f[n][5] * r2;
                s_h[n][6][kk] = f[n][6] * r2;
                s_h[n][7][kk] = f[n][7] * r2;
                s_h[n][8][kk] = f[n][8] * r2;
            }
        }

        // peel: batch-0 weight loads don't depend on s_h -> issue BEFORE barrier
        float4 wv0[3][2];
        LOADWQ(wv0, 0);
        __syncthreads();   // s_h visible; also orders prev-iter s_part reads
                           // vs this iter's s_tp rewrite, and sUp build (it==0)

        // ---------- step 2: linear_in, packed 16B loads, unroll-2 hoisting ----
        float hcA[NB][9], hcB[NB][9];   // A = col 2t, B = col 2t+1
        {
            #pragma unroll
            for (int n = 0; n < NB; ++n)
                #pragma unroll
                for (int m = 0; m < 9; ++m) { hcA[n][m] = 0.0f; hcB[n][m] = 0.0f; }

            INSTEPQ(wv0, 0);
            #pragma unroll 2
            for (int kb = 4; kb < KCH; kb += 4) {
                float4 wv[3][2];
                LOADWQ(wv, kb);
                INSTEPQ(wv, kb);
            }
        }

        // ---------- step 3: CG tensor product (registers) ----------
        const float* Q0 = PV + (size_t)(it * 3 + 0) * 128 * 64 * 4 + 4 * ln;
        const float* Q1 = PV + (size_t)(it * 3 + 1) * 128 * 64 * 4 + 4 * ln;
        const float* Q2 = PV + (size_t)(it * 3 + 2) * 128 * 64 * 4 + 4 * ln;
        const int pb0 = w * 128;   // this wave's p-half (uniform)
        float4 vv0[3][2];
        {
            float tpA[NB][9], tpB[NB][9];
            #pragma unroll
            for (int n = 0; n < NB; ++n)
                #pragma unroll
                for (int c = 0; c < 9; ++c) { tpA[n][c] = 0.0f; tpB[n][c] = 0.0f; }

            int ab = 0;
            #pragma unroll
            for (int a = 0; a < 9; ++a) {
                #pragma unroll
                for (int b = a; b < 9; ++b) {
                    const float qA0 = hcA[0][a] * hcA[0][b];
                    const float qA1 = hcA[1][a] * hcA[1][b];
                    const float qB0 = hcB[0][a] * hcB[0][b];
                    const float qB1 = hcB[1][a] * hcB[1][b];
                    const float4 u0 = *(const float4*)&sUp[ab][0];
                    const float4 u1 = *(const float4*)&sUp[ab][4];
                    const float  u8 = sUp[ab][8];
                    const float uu[9] = {u0.x, u0.y, u0.z, u0.w, u1.x, u1.y, u1.z, u1.w, u8};
                    #pragma unroll
                    for (int c = 0; c < 9; ++c) {
                        tpA[0][c] = fmaf(uu[c], qA0, tpA[0][c]);
                        tpA[1][c] = fmaf(uu[c], qA1, tpA[1][c]);
                        tpB[0][c] = fmaf(uu[c], qB0, tpB[0][c]);
                        tpB[1][c] = fmaf(uu[c], qB1, tpB[1][c]);
                    }
                    ++ab;
                }
            }

            // peel: lin_out batch-0 loads hide under s_tp writes + barrier
            LOADVQ(vv0, 0);

            #pragma unroll
            for (int n = 0; n < NB; ++n) {
                #pragma unroll
                for (int c = 0; c < 9; ++c) {
                    float2 t2; t2.x = tpA[n][c]; t2.y = tpB[n][c];
                    *(float2*)&s_tp[n][c][2 * tid] = t2;
                }
            }
        }
        __syncthreads();   // s_tp visible to all columns

        // ---------- step 4: linear_out, packed 16B loads, unroll-2 hoisting ----
        float oaA[NB][9], oaB[NB][9];   // kkA = 2*ln, kkB = 2*ln+1
        {
            #pragma unroll
            for (int n = 0; n < NB; ++n)
                #pragma unroll
                for (int m = 0; m < 9; ++m) { oaA[n][m] = 0.0f; oaB[n][m] = 0.0f; }

            OUTSTEPQ(vv0, 0);
            #pragma unroll 2
            for (int pb = 4; pb < 128; pb += 4) {
                float4 vv[3][2];
                LOADVQ(vv, pb);
                OUTSTEPQ(vv, pb);
            }
        }
        __syncthreads();   // ALL s_tp reads done -> safe to overwrite as s_part

        #pragma unroll
        for (int n = 0; n < NB; ++n) {
            #pragma unroll
            for (int m = 0; m < 9; ++m) {
                float2 t2; t2.x = oaA[n][m]; t2.y = oaB[n][m];
                *(float2*)&s_part[w][n * 9 + m][2 * ln] = t2;
            }
        }
        __syncthreads();

        #pragma unroll
        for (int n = 0; n < NB; ++n)
            #pragma unroll
            for (int m = 0; m < 9; ++m)
                f[n][m] += s_part[0][n * 9 + m][kk] + s_part[1][n * 9 + m][kk];
        // no end-of-iter barrier: next iter's RMS writes s_h (disjoint buffer);
        // the post-RMS barrier orders these s_part reads vs the next s_tp writes.
    }

    #pragma unroll
    for (int n = 0; n < NB; ++n) {
        const int ng = node0 + n;
        #pragma unroll
        for (int m = 0; m < 9; ++m)
            out[(size_t)(ng * 9 + m) * KCH + kk] = f[n][m];
    }
}

// ---------------- fallback kernel: byte-identical r7 ---------------------
__global__ __launch_bounds__(NTHR, 4)
void cg_fused_fb(const float* __restrict__ f0,
                 const float* __restrict__ f1,
                 const float* __restrict__ f2,
                 const float* __restrict__ Uin,
                 const float* __restrict__ gamma,
                 const float* __restrict__ W_in,
                 const float* __restrict__ W_out,
                 float* __restrict__ out)
{
    __shared__ float sUp[45][12];
    __shared__ float s_h[NB][9][KCH];
    __shared__ float s_tp[NB][9][PCH];
    float (*s_part)[18][KCH] = reinterpret_cast<float (*)[18][KCH]>(&s_tp[0][0][0]);

    const int tid = threadIdx.x;
    const int w   = tid >> 6;
    const int ln  = tid & 63;
    const int kk  = tid;
    const int node0 = blockIdx.x * NB;

    for (int idx = tid; idx < 45 * 12; idx += NTHR) {
        const int ab = idx / 12;
        const int c  = idx % 12;
        int a = 0, r = ab;
        while (r >= 9 - a) { r -= 9 - a; ++a; }
        const int b = a + r;
        float v = 0.0f;
        if (c < 9) {
            v = Uin[(a * 9 + b) * 9 + c];
            if (a != b) v += Uin[(b * 9 + a) * 9 + c];
        }
        sUp[ab][c] = v;
    }

    float f[NB][9];
    #pragma unroll
    for (int n = 0; n < NB; ++n) {
        const int ng = node0 + n;
        f[n][0] = f0[ng * KCH + kk];
        #pragma unroll
        for (int m = 0; m < 3; ++m) f[n][1 + m] = f1[(ng * 3 + m) * KCH + kk];
        #pragma unroll
        for (int m = 0; m < 5; ++m) f[n][4 + m] = f2[(ng * 5 + m) * KCH + kk];
    }

    for (int it = 0; it < NITER; ++it) {
        {
            const float g0 = gamma[(it * 3 + 0) * KCH + kk];
            const float g1 = gamma[(it * 3 + 1) * KCH + kk];
            const float g2 = gamma[(it * 3 + 2) * KCH + kk];
            #pragma unroll
            for (int n = 0; n < NB; ++n) {
                const float s0 = f[n][0] * f[n][0];
                const float s1 = f[n][1] * f[n][1] + f[n][2] * f[n][2] + f[n][3] * f[n][3];
                const float s2 = f[n][4] * f[n][4] + f[n][5] * f[n][5] + f[n][6] * f[n][6]
                               + f[n][7] * f[n][7] + f[n][8] * f[n][8];
                const float r0 = rsqrtf(s0 + 1e-6f) * g0;
                const float r1 = rsqrtf(s1 * (1.0f / 3.0f) + 1e-6f) * g1;
                const float r2 = rsqrtf(s2 * (1.0f / 5.0f) + 1e-6f) * g2;
                s_h[n][0][kk] = f[n][0] * r0;
                s_h[n][1][kk] = f[n][1] * r1;
                s_h[n][2][kk] = f[n][2] * r1;
                s_h[n][3][kk] = f[n][3] * r1;
                s_h[n][4][kk] = f[n][4] * r2;
                s_h[n][5][kk] = f[n][5] * r2;
                s_h[n][6][kk] = f[n][6] * r2;
                s_h[n][7][kk] = f[n][7] * r2;
                s_h[n][8][kk] = f[n][8] * r2;
            }
        }
        __syncthreads();

        float hcA[NB][9], hcB[NB][9];
        {
            const float* W0 = W_in + (size_t)(it * 3 + 0) * KCH * PCH + 2 * tid;
            const float* W1 = W_in + (size_t)(it * 3 + 1) * KCH * PCH + 2 * tid;
            const float* W2 = W_in + (size_t)(it * 3 + 2) * KCH * PCH + 2 * tid;
            #pragma unroll
            for (int n = 0; n < NB; ++n)
                #pragma unroll
                for (int m = 0; m < 9; ++m) { hcA[n][m] = 0.0f; hcB[n][m] = 0.0f; }

            #pragma unroll 1
            for (int kb = 0; kb < KCH; kb += 4) {
                float2 wv[3][4];
                #pragma unroll
                for (int r = 0; r < 4; ++r) {
                    wv[0][r] = *(const float2*)&W0[(kb + r) * PCH];
                    wv[1][r] = *(const float2*)&W1[(kb + r) * PCH];
                    wv[2][r] = *(const float2*)&W2[(kb + r) * PCH];
                }
                #pragma unroll
                for (int n = 0; n < NB; ++n) {
                    #pragma unroll
                    for (int m = 0; m < 9; ++m) {
                        const int lm = (m == 0) ? 0 : ((m < 4) ? 1 : 2);
                        const float4 h4 = *(const float4*)&s_h[n][m][kb];
                        float a = hcA[n][m], b = hcB[n][m];
                        a = fmaf(h4.x, wv[lm][0].x, a);
                        a = fmaf(h4.y, wv[lm][1].x, a);
                        a = fmaf(h4.z, wv[lm][2].x, a);
                        a = fmaf(h4.w, wv[lm][3].x, a);
                        b = fmaf(h4.x, wv[lm][0].y, b);
                        b = fmaf(h4.y, wv[lm][1].y, b);
                        b = fmaf(h4.z, wv[lm][2].y, b);
                        b = fmaf(h4.w, wv[lm][3].y, b);
                        hcA[n][m] = a; hcB[n][m] = b;
                    }
                }
            }
        }

        {
            float tpA[NB][9], tpB[NB][9];
            #pragma unroll
            for (int n = 0; n < NB; ++n)
                #pragma unroll
                for (int c = 0; c < 9; ++c) { tpA[n][c] = 0.0f; tpB[n][c] = 0.0f; }

            int ab = 0;
            #pragma unroll
            for (int a = 0; a < 9; ++a) {
                #pragma unroll
                for (int b = a; b < 9; ++b) {
                    const float qA0 = hcA[0][a] * hcA[0][b];
                    const float qA1 = hcA[1][a] * hcA[1][b];
                    const float qB0 = hcB[0][a] * hcB[0][b];
                    const float qB1 = hcB[1][a] * hcB[1][b];
                    const float4 u0 = *(const float4*)&sUp[ab][0];
                    const float4 u1 = *(const float4*)&sUp[ab][4];
                    const float  u8 = sUp[ab][8];
                    const float uu[9] = {u0.x, u0.y, u0.z, u0.w, u1.x, u1.y, u1.z, u1.w, u8};
                    #pragma unroll
                    for (int c = 0; c < 9; ++c) {
                        tpA[0][c] = fmaf(uu[c], qA0, tpA[0][c]);
                        tpA[1][c] = fmaf(uu[c], qA1, tpA[1][c]);
                        tpB[0][c] = fmaf(uu[c], qB0, tpB[0][c]);
                        tpB[1][c] = fmaf(uu[c], qB1, tpB[1][c]);
                    }
                    ++ab;
                }
            }
            #pragma unroll
            for (int n = 0; n < NB; ++n) {
                #pragma unroll
                for (int c = 0; c < 9; ++c) {
                    float2 t2; t2.x = tpA[n][c]; t2.y = tpB[n][c];
                    *(float2*)&s_tp[n][c][2 * tid] = t2;
                }
            }
        }
        __syncthreads();

        float oaA[NB][9], oaB[NB][9];
        {
            const float* V0 = W_out + (size_t)(it * 3 + 0) * PCH * KCH + 2 * ln;
            const float* V1 = W_out + (size_t)(it * 3 + 1) * PCH * KCH + 2 * ln;
            const float* V2 = W_out + (size_t)(it * 3 + 2) * PCH * KCH + 2 * ln;
            const int pb0 = w * 128;

            #pragma unroll
            for (int n = 0; n < NB; ++n)
                #pragma unroll
                for (int m = 0; m < 9; ++m) { oaA[n][m] = 0.0f; oaB[n][m] = 0.0f; }

            #pragma unroll 1
            for (int pb = 0; pb < 128; pb += 4) {
                float2 vv[3][4];
                #pragma unroll
                for (int r = 0; r < 4; ++r) {
                    const size_t row = (size_t)(pb0 + pb + r) * KCH;
                    vv[0][r] = *(const float2*)&V0[row];
                    vv[1][r] = *(const float2*)&V1[row];
                    vv[2][r] = *(const float2*)&V2[row];
                }
                #pragma unroll
                for (int n = 0; n < NB; ++n) {
                    #pragma unroll
                    for (int m = 0; m < 9; ++m) {
                        const int lm = (m == 0) ? 0 : ((m < 4) ? 1 : 2);
                        const float4 t4 = *(const float4*)&s_tp[n][m][pb0 + pb];
                        float a = oaA[n][m], b = oaB[n][m];
                        a = fmaf(t4.x, vv[lm][0].x, a);
                        a = fmaf(t4.y, vv[lm][1].x, a);
                        a = fmaf(t4.z, vv[lm][2].x, a);
                        a = fmaf(t4.w, vv[lm][3].x, a);
                        b = fmaf(t4.x, vv[lm][0].y, b);
                        b = fmaf(t4.y, vv[lm][1].y, b);
                        b = fmaf(t4.z, vv[lm][2].y, b);
                        b = fmaf(t4.w, vv[lm][3].y, b);
                        oaA[n][m] = a; oaB[n][m] = b;
                    }
                }
            }
        }
        __syncthreads();

        #pragma unroll
        for (int n = 0; n < NB; ++n) {
            #pragma unroll
            for (int m = 0; m < 9; ++m) {
                float2 t2; t2.x = oaA[n][m]; t2.y = oaB[n][m];
                *(float2*)&s_part[w][n * 9 + m][2 * ln] = t2;
            }
        }
        __syncthreads();

        #pragma unroll
        for (int n = 0; n < NB; ++n)
            #pragma unroll
            for (int m = 0; m < 9; ++m)
                f[n][m] += s_part[0][n * 9 + m][kk] + s_part[1][n * 9 + m][kk];
        __syncthreads();
    }

    #pragma unroll
    for (int n = 0; n < NB; ++n) {
        const int ng = node0 + n;
        #pragma unroll
        for (int m = 0; m < 9; ++m)
            out[(size_t)(ng * 9 + m) * KCH + kk] = f[n][m];
    }
}

extern "C" void kernel_launch(void* const* d_in, const int* in_sizes, int n_in,
                              void* d_out, int out_size, void* d_ws, size_t ws_size,
                              hipStream_t stream) {
    const float* f0    = (const float*)d_in[0];
    const float* f1    = (const float*)d_in[1];
    const float* f2    = (const float*)d_in[2];
    const float* U     = (const float*)d_in[3];
    const float* gamma = (const float*)d_in[4];
    const float* W_in  = (const float*)d_in[5];
    const float* W_out = (const float*)d_in[6];
    float* out = (float*)d_out;

    if (d_ws != nullptr && ws_size >= PACK_BYTES) {
        float* PW = (float*)d_ws;
        float* PV = PW + (size_t)PW_QUADS * 4;
        const int total = PW_QUADS + PV_QUADS;
        dim3 pgrid((total + 255) / 256), pblock(256);
        hipLaunchKernelGGL(pack_weights, pgrid, pblock, 0, stream,
                           W_in, W_out, PW, PV);
        dim3 grid(NNODES / NB), block(NTHR);
        hipLaunchKernelGGL(cg_fused_pk, grid, block, 0, stream,
                           f0, f1, f2, U, gamma, PW, PV, out);
    } else {
        dim3 grid(NNODES / NB), block(NTHR);
        hipLaunchKernelGGL(cg_fused_fb, grid, block, 0, stream,
                           f0, f1, f2, U, gamma, W_in, W_out, out);
    }
}

// Round 15
// 4426.867 us; speedup vs baseline: 1.0133x; 1.0133x over previous
//
#include <hip/hip_runtime.h>

// CGIterator: N=50000 nodes, K=128, I=4 chained CG iterations, fp32.
// FINAL (= round-13 verbatim, the session's best clean kernel: 4461 us bench,
// ~5.0 ms rocprof, VGPR 116, zero spill).
// Structure: 128 thr (2 waves), NB=2 nodes/block, TN=2 consecutive columns,
// packed 16B weight quads in d_ws (2 cols x 2 rows per dwordx4 -> 384 VMEM
// instrs/wave-iter, the twice-confirmed ~9cyc/instr lever), LDS 30.2 KB,
// launch_bounds(128,4) — the only allocator-stable config found.
// Plateau arithmetic (12M cyc): FMA issue 36% (fp32 floor, no MFMA path),
// VMEM service 22% (max width, NB=4 spills), LDS 17% (non-binding, r5),
// stalls 25% (dbuf/occupancy/hoisting all closed by r8-r14 measurements).

#define NNODES 50000
#define KCH 128          // K
#define PCH 256          // 2K
#define NITER 4
#define NB 2             // nodes per block
#define NTHR 128

#define PW_QUADS (12 * 64 * 128)     // g(12) x k2(64) x t(128), 16B each
#define PV_QUADS (12 * 128 * 64)     // g(12) x p2(128) x ln(64), 16B each
#define PACK_BYTES ((size_t)(PW_QUADS + PV_QUADS) * 16)

// ---------------- pack kernel (once per launch, ~6 MB of HBM traffic) ----
__global__ __launch_bounds__(256)
void pack_weights(const float* __restrict__ W_in, const float* __restrict__ W_out,
                  float* __restrict__ PW, float* __restrict__ PV)
{
    const int idx = blockIdx.x * 256 + threadIdx.x;
    if (idx < PW_QUADS) {
        const int t  = idx & 127;
        const int k2 = (idx >> 7) & 63;
        const int g  = idx >> 13;
        const float* src = W_in + (size_t)g * KCH * PCH;
        float4 v;
        v.x = src[(2 * k2    ) * PCH + 2 * t    ];
        v.y = src[(2 * k2    ) * PCH + 2 * t + 1];
        v.z = src[(2 * k2 + 1) * PCH + 2 * t    ];
        v.w = src[(2 * k2 + 1) * PCH + 2 * t + 1];
        *(float4*)&PW[(size_t)idx * 4] = v;
    } else if (idx < PW_QUADS + PV_QUADS) {
        const int j  = idx - PW_QUADS;
        const int ln = j & 63;
        const int p2 = (j >> 6) & 127;
        const int g  = j >> 13;
        const float* src = W_out + (size_t)g * PCH * KCH;
        float4 v;
        v.x = src[(2 * p2    ) * KCH + 2 * ln    ];
        v.y = src[(2 * p2    ) * KCH + 2 * ln + 1];
        v.z = src[(2 * p2 + 1) * KCH + 2 * ln    ];
        v.w = src[(2 * p2 + 1) * KCH + 2 * ln + 1];
        *(float4*)&PV[(size_t)j * 4] = v;
    }
}

// ---------------- main kernel (packed weights) ---------------------------
__global__ __launch_bounds__(NTHR, 4)
void cg_fused_pk(const float* __restrict__ f0,
                 const float* __restrict__ f1,
                 const float* __restrict__ f2,
                 const float* __restrict__ Uin,
                 const float* __restrict__ gamma,
                 const float* __restrict__ PW,
                 const float* __restrict__ PV,
                 float* __restrict__ out)
{
    __shared__ float sUp[45][12];                 // 2.1 KB
    __shared__ float s_h[NB][9][KCH];             // 9.2 KB
    __shared__ float s_tp[NB][9][PCH];            // 18.4 KB; exchange overlay
    float (*s_part)[18][KCH] = reinterpret_cast<float (*)[18][KCH]>(&s_tp[0][0][0]);

    const int tid = threadIdx.x;      // 0..127
    const int w   = tid >> 6;         // wave: 0 or 1 (uniform)
    const int ln  = tid & 63;
    const int kk  = tid;
    const int node0 = blockIdx.x * NB;

    for (int idx = tid; idx < 45 * 12; idx += NTHR) {
        const int ab = idx / 12;
        const int c  = idx % 12;
        int a = 0, r = ab;
        while (r >= 9 - a) { r -= 9 - a; ++a; }
        const int b = a + r;
        float v = 0.0f;
        if (c < 9) {
            v = Uin[(a * 9 + b) * 9 + c];
            if (a != b) v += Uin[(b * 9 + a) * 9 + c];
        }
        sUp[ab][c] = v;
    }

    float f[NB][9];
    #pragma unroll
    for (int n = 0; n < NB; ++n) {
        const int ng = node0 + n;
        f[n][0] = f0[ng * KCH + kk];
        #pragma unroll
        for (int m = 0; m < 3; ++m) f[n][1 + m] = f1[(ng * 3 + m) * KCH + kk];
        #pragma unroll
        for (int m = 0; m < 5; ++m) f[n][4 + m] = f2[(ng * 5 + m) * KCH + kk];
    }

    for (int it = 0; it < NITER; ++it) {
        // ---------- step 1: RMS norm -> s_h ----------
        {
            const float g0 = gamma[(it * 3 + 0) * KCH + kk];
            const float g1 = gamma[(it * 3 + 1) * KCH + kk];
            const float g2 = gamma[(it * 3 + 2) * KCH + kk];
            #pragma unroll
            for (int n = 0; n < NB; ++n) {
                const float s0 = f[n][0] * f[n][0];
                const float s1 = f[n][1] * f[n][1] + f[n][2] * f[n][2] + f[n][3] * f[n][3];
                const float s2 = f[n][4] * f[n][4] + f[n][5] * f[n][5] + f[n][6] * f[n][6]
                               + f[n][7] * f[n][7] + f[n][8] * f[n][8];
                const float r0 = rsqrtf(s0 + 1e-6f) * g0;
                const float r1 = rsqrtf(s1 * (1.0f / 3.0f) + 1e-6f) * g1;
                const float r2 = rsqrtf(s2 * (1.0f / 5.0f) + 1e-6f) * g2;
                s_h[n][0][kk] = f[n][0] * r0;
                s_h[n][1][kk] = f[n][1] * r1;
                s_h[n][2][kk] = f[n][2] * r1;
                s_h[n][3][kk] = f[n][3] * r1;
                s_h[n][4][kk] = f[n][4] * r2;
                s_h[n][5][kk] = f[n][5] * r2;
                s_h[n][6][kk] = f[n][6] * r2;
                s_h[n][7][kk] = f[n][7] * r2;
                s_h[n][8][kk] = f[n][8] * r2;
            }
        }
        __syncthreads();   // s_h visible; also orders prev-iter s_part reads
                           // vs this iter's s_tp rewrite, and sUp build (it==0)

        // ---------- step 2: linear_in, packed 16B weight loads ----------
        float hcA[NB][9], hcB[NB][9];   // A = col 2t, B = col 2t+1
        {
            // PW block for (it,l): quads laid out [k2][t][4]
            const float* P0 = PW + (size_t)(it * 3 + 0) * 64 * 128 * 4 + 4 * tid;
            const float* P1 = PW + (size_t)(it * 3 + 1) * 64 * 128 * 4 + 4 * tid;
            const float* P2 = PW + (size_t)(it * 3 + 2) * 64 * 128 * 4 + 4 * tid;
            #pragma unroll
            for (int n = 0; n < NB; ++n)
                #pragma unroll
                for (int m = 0; m < 9; ++m) { hcA[n][m] = 0.0f; hcB[n][m] = 0.0f; }

            #pragma unroll 1
            for (int kb = 0; kb < KCH; kb += 4) {
                const int k2 = kb >> 1;            // row-pair index
                float4 wv[3][2];
                #pragma unroll
                for (int r = 0; r < 2; ++r) {
                    wv[0][r] = *(const float4*)&P0[(size_t)(k2 + r) * 128 * 4];
                    wv[1][r] = *(const float4*)&P1[(size_t)(k2 + r) * 128 * 4];
                    wv[2][r] = *(const float4*)&P2[(size_t)(k2 + r) * 128 * 4];
                }
                #pragma unroll
                for (int n = 0; n < NB; ++n) {
                    #pragma unroll
                    for (int m = 0; m < 9; ++m) {
                        const int lm = (m == 0) ? 0 : ((m < 4) ? 1 : 2);
                        const float4 h4 = *(const float4*)&s_h[n][m][kb];
                        float a = hcA[n][m], b = hcB[n][m];
                        a = fmaf(h4.x, wv[lm][0].x, a);   // k=kb
                        b = fmaf(h4.x, wv[lm][0].y, b);
                        a = fmaf(h4.y, wv[lm][0].z, a);   // k=kb+1
                        b = fmaf(h4.y, wv[lm][0].w, b);
                        a = fmaf(h4.z, wv[lm][1].x, a);   // k=kb+2
                        b = fmaf(h4.z, wv[lm][1].y, b);
                        a = fmaf(h4.w, wv[lm][1].z, a);   // k=kb+3
                        b = fmaf(h4.w, wv[lm][1].w, b);
                        hcA[n][m] = a; hcB[n][m] = b;
                    }
                }
            }
        }

        // ---------- step 3: CG tensor product (registers) ----------
        {
            float tpA[NB][9], tpB[NB][9];
            #pragma unroll
            for (int n = 0; n < NB; ++n)
                #pragma unroll
                for (int c = 0; c < 9; ++c) { tpA[n][c] = 0.0f; tpB[n][c] = 0.0f; }

            int ab = 0;
            #pragma unroll
            for (int a = 0; a < 9; ++a) {
                #pragma unroll
                for (int b = a; b < 9; ++b) {
                    const float qA0 = hcA[0][a] * hcA[0][b];
                    const float qA1 = hcA[1][a] * hcA[1][b];
                    const float qB0 = hcB[0][a] * hcB[0][b];
                    const float qB1 = hcB[1][a] * hcB[1][b];
                    const float4 u0 = *(const float4*)&sUp[ab][0];
                    const float4 u1 = *(const float4*)&sUp[ab][4];
                    const float  u8 = sUp[ab][8];
                    const float uu[9] = {u0.x, u0.y, u0.z, u0.w, u1.x, u1.y, u1.z, u1.w, u8};
                    #pragma unroll
                    for (int c = 0; c < 9; ++c) {
                        tpA[0][c] = fmaf(uu[c], qA0, tpA[0][c]);
                        tpA[1][c] = fmaf(uu[c], qA1, tpA[1][c]);
                        tpB[0][c] = fmaf(uu[c], qB0, tpB[0][c]);
                        tpB[1][c] = fmaf(uu[c], qB1, tpB[1][c]);
                    }
                    ++ab;
                }
            }
            #pragma unroll
            for (int n = 0; n < NB; ++n) {
                #pragma unroll
                for (int c = 0; c < 9; ++c) {
                    float2 t2; t2.x = tpA[n][c]; t2.y = tpB[n][c];
                    *(float2*)&s_tp[n][c][2 * tid] = t2;
                }
            }
        }
        __syncthreads();   // s_tp visible to all columns

        // ---------- step 4: linear_out, p-half per wave, packed 16B loads ----
        float oaA[NB][9], oaB[NB][9];   // kkA = 2*ln, kkB = 2*ln+1
        {
            const float* Q0 = PV + (size_t)(it * 3 + 0) * 128 * 64 * 4 + 4 * ln;
            const float* Q1 = PV + (size_t)(it * 3 + 1) * 128 * 64 * 4 + 4 * ln;
            const float* Q2 = PV + (size_t)(it * 3 + 2) * 128 * 64 * 4 + 4 * ln;
            const int pb0 = w * 128;   // this wave's p-half (uniform)

            #pragma unroll
            for (int n = 0; n < NB; ++n)
                #pragma unroll
                for (int m = 0; m < 9; ++m) { oaA[n][m] = 0.0f; oaB[n][m] = 0.0f; }

            #pragma unroll 1
            for (int pb = 0; pb < 128; pb += 4) {
                const int p2 = (pb0 + pb) >> 1;    // row-pair index
                float4 vv[3][2];
                #pragma unroll
                for (int r = 0; r < 2; ++r) {
                    vv[0][r] = *(const float4*)&Q0[(size_t)(p2 + r) * 64 * 4];
                    vv[1][r] = *(const float4*)&Q1[(size_t)(p2 + r) * 64 * 4];
                    vv[2][r] = *(const float4*)&Q2[(size_t)(p2 + r) * 64 * 4];
                }
                #pragma unroll
                for (int n = 0; n < NB; ++n) {
                    #pragma unroll
                    for (int m = 0; m < 9; ++m) {
                        const int lm = (m == 0) ? 0 : ((m < 4) ? 1 : 2);
                        const float4 t4 = *(const float4*)&s_tp[n][m][pb0 + pb];
                        float a = oaA[n][m], b = oaB[n][m];
                        a = fmaf(t4.x, vv[lm][0].x, a);   // p=pb0+pb
                        b = fmaf(t4.x, vv[lm][0].y, b);
                        a = fmaf(t4.y, vv[lm][0].z, a);   // p+1
                        b = fmaf(t4.y, vv[lm][0].w, b);
                        a = fmaf(t4.z, vv[lm][1].x, a);   // p+2
                        b = fmaf(t4.z, vv[lm][1].y, b);
                        a = fmaf(t4.w, vv[lm][1].z, a);   // p+3
                        b = fmaf(t4.w, vv[lm][1].w, b);
                        oaA[n][m] = a; oaB[n][m] = b;
                    }
                }
            }
        }
        __syncthreads();   // ALL s_tp reads done -> safe to overwrite as s_part

        #pragma unroll
        for (int n = 0; n < NB; ++n) {
            #pragma unroll
            for (int m = 0; m < 9; ++m) {
                float2 t2; t2.x = oaA[n][m]; t2.y = oaB[n][m];
                *(float2*)&s_part[w][n * 9 + m][2 * ln] = t2;
            }
        }
        __syncthreads();

        #pragma unroll
        for (int n = 0; n < NB; ++n)
            #pragma unroll
            for (int m = 0; m < 9; ++m)
                f[n][m] += s_part[0][n * 9 + m][kk] + s_part[1][n * 9 + m][kk];
        // no end-of-iter barrier: next iter's RMS writes s_h (disjoint buffer);
        // the post-RMS barrier orders these s_part reads vs the next s_tp writes.
    }

    #pragma unroll
    for (int n = 0; n < NB; ++n) {
        const int ng = node0 + n;
        #pragma unroll
        for (int m = 0; m < 9; ++m)
            out[(size_t)(ng * 9 + m) * KCH + kk] = f[n][m];
    }
}

// ---------------- fallback kernel: byte-identical r7 ---------------------
__global__ __launch_bounds__(NTHR, 4)
void cg_fused_fb(const float* __restrict__ f0,
                 const float* __restrict__ f1,
                 const float* __restrict__ f2,
                 const float* __restrict__ Uin,
                 const float* __restrict__ gamma,
                 const float* __restrict__ W_in,
                 const float* __restrict__ W_out,
                 float* __restrict__ out)
{
    __shared__ float sUp[45][12];
    __shared__ float s_h[NB][9][KCH];
    __shared__ float s_tp[NB][9][PCH];
    float (*s_part)[18][KCH] = reinterpret_cast<float (*)[18][KCH]>(&s_tp[0][0][0]);

    const int tid = threadIdx.x;
    const int w   = tid >> 6;
    const int ln  = tid & 63;
    const int kk  = tid;
    const int node0 = blockIdx.x * NB;

    for (int idx = tid; idx < 45 * 12; idx += NTHR) {
        const int ab = idx / 12;
        const int c  = idx % 12;
        int a = 0, r = ab;
        while (r >= 9 - a) { r -= 9 - a; ++a; }
        const int b = a + r;
        float v = 0.0f;
        if (c < 9) {
            v = Uin[(a * 9 + b) * 9 + c];
            if (a != b) v += Uin[(b * 9 + a) * 9 + c];
        }
        sUp[ab][c] = v;
    }

    float f[NB][9];
    #pragma unroll
    for (int n = 0; n < NB; ++n) {
        const int ng = node0 + n;
        f[n][0] = f0[ng * KCH + kk];
        #pragma unroll
        for (int m = 0; m < 3; ++m) f[n][1 + m] = f1[(ng * 3 + m) * KCH + kk];
        #pragma unroll
        for (int m = 0; m < 5; ++m) f[n][4 + m] = f2[(ng * 5 + m) * KCH + kk];
    }

    for (int it = 0; it < NITER; ++it) {
        {
            const float g0 = gamma[(it * 3 + 0) * KCH + kk];
            const float g1 = gamma[(it * 3 + 1) * KCH + kk];
            const float g2 = gamma[(it * 3 + 2) * KCH + kk];
            #pragma unroll
            for (int n = 0; n < NB; ++n) {
                const float s0 = f[n][0] * f[n][0];
                const float s1 = f[n][1] * f[n][1] + f[n][2] * f[n][2] + f[n][3] * f[n][3];
                const float s2 = f[n][4] * f[n][4] + f[n][5] * f[n][5] + f[n][6] * f[n][6]
                               + f[n][7] * f[n][7] + f[n][8] * f[n][8];
                const float r0 = rsqrtf(s0 + 1e-6f) * g0;
                const float r1 = rsqrtf(s1 * (1.0f / 3.0f) + 1e-6f) * g1;
                const float r2 = rsqrtf(s2 * (1.0f / 5.0f) + 1e-6f) * g2;
                s_h[n][0][kk] = f[n][0] * r0;
                s_h[n][1][kk] = f[n][1] * r1;
                s_h[n][2][kk] = f[n][2] * r1;
                s_h[n][3][kk] = f[n][3] * r1;
                s_h[n][4][kk] = f[n][4] * r2;
                s_h[n][5][kk] = f[n][5] * r2;
                s_h[n][6][kk] = f[n][6] * r2;
                s_h[n][7][kk] = f[n][7] * r2;
                s_h[n][8][kk] = f[n][8] * r2;
            }
        }
        __syncthreads();

        float hcA[NB][9], hcB[NB][9];
        {
            const float* W0 = W_in + (size_t)(it * 3 + 0) * KCH * PCH + 2 * tid;
            const float* W1 = W_in + (size_t)(it * 3 + 1) * KCH * PCH + 2 * tid;
            const float* W2 = W_in + (size_t)(it * 3 + 2) * KCH * PCH + 2 * tid;
            #pragma unroll
            for (int n = 0; n < NB; ++n)
                #pragma unroll
                for (int m = 0; m < 9; ++m) { hcA[n][m] = 0.0f; hcB[n][m] = 0.0f; }

            #pragma unroll 1
            for (int kb = 0; kb < KCH; kb += 4) {
                float2 wv[3][4];
                #pragma unroll
                for (int r = 0; r < 4; ++r) {
                    wv[0][r] = *(const float2*)&W0[(kb + r) * PCH];
                    wv[1][r] = *(const float2*)&W1[(kb + r) * PCH];
                    wv[2][r] = *(const float2*)&W2[(kb + r) * PCH];
                }
                #pragma unroll
                for (int n = 0; n < NB; ++n) {
                    #pragma unroll
                    for (int m = 0; m < 9; ++m) {
                        const int lm = (m == 0) ? 0 : ((m < 4) ? 1 : 2);
                        const float4 h4 = *(const float4*)&s_h[n][m][kb];
                        float a = hcA[n][m], b = hcB[n][m];
                        a = fmaf(h4.x, wv[lm][0].x, a);
                        a = fmaf(h4.y, wv[lm][1].x, a);
                        a = fmaf(h4.z, wv[lm][2].x, a);
                        a = fmaf(h4.w, wv[lm][3].x, a);
                        b = fmaf(h4.x, wv[lm][0].y, b);
                        b = fmaf(h4.y, wv[lm][1].y, b);
                        b = fmaf(h4.z, wv[lm][2].y, b);
                        b = fmaf(h4.w, wv[lm][3].y, b);
                        hcA[n][m] = a; hcB[n][m] = b;
                    }
                }
            }
        }

        {
            float tpA[NB][9], tpB[NB][9];
            #pragma unroll
            for (int n = 0; n < NB; ++n)
                #pragma unroll
                for (int c = 0; c < 9; ++c) { tpA[n][c] = 0.0f; tpB[n][c] = 0.0f; }

            int ab = 0;
            #pragma unroll
            for (int a = 0; a < 9; ++a) {
                #pragma unroll
                for (int b = a; b < 9; ++b) {
                    const float qA0 = hcA[0][a] * hcA[0][b];
                    const float qA1 = hcA[1][a] * hcA[1][b];
                    const float qB0 = hcB[0][a] * hcB[0][b];
                    const float qB1 = hcB[1][a] * hcB[1][b];
                    const float4 u0 = *(const float4*)&sUp[ab][0];
                    const float4 u1 = *(const float4*)&sUp[ab][4];
                    const float  u8 = sUp[ab][8];
                    const float uu[9] = {u0.x, u0.y, u0.z, u0.w, u1.x, u1.y, u1.z, u1.w, u8};
                    #pragma unroll
                    for (int c = 0; c < 9; ++c) {
                        tpA[0][c] = fmaf(uu[c], qA0, tpA[0][c]);
                        tpA[1][c] = fmaf(uu[c], qA1, tpA[1][c]);
                        tpB[0][c] = fmaf(uu[c], qB0, tpB[0][c]);
                        tpB[1][c] = fmaf(uu[c], qB1, tpB[1][c]);
                    }
                    ++ab;
                }
            }
            #pragma unroll
            for (int n = 0; n < NB; ++n) {
                #pragma unroll
                for (int c = 0; c < 9; ++c) {
                    float2 t2; t2.x = tpA[n][c]; t2.y = tpB[n][c];
                    *(float2*)&s_tp[n][c][2 * tid] = t2;
                }
            }
        }
        __syncthreads();

        float oaA[NB][9], oaB[NB][9];
        {
            const float* V0 = W_out + (size_t)(it * 3 + 0) * PCH * KCH + 2 * ln;
            const float* V1 = W_out + (size_t)(it * 3 + 1) * PCH * KCH + 2 * ln;
            const float* V2 = W_out + (size_t)(it * 3 + 2) * PCH * KCH + 2 * ln;
            const int pb0 = w * 128;

            #pragma unroll
            for (int n = 0; n < NB; ++n)
                #pragma unroll
                for (int m = 0; m < 9; ++m) { oaA[n][m] = 0.0f; oaB[n][m] = 0.0f; }

            #pragma unroll 1
            for (int pb = 0; pb < 128; pb += 4) {
                float2 vv[3][4];
                #pragma unroll
                for (int r = 0; r < 4; ++r) {
                    const size_t row = (size_t)(pb0 + pb + r) * KCH;
                    vv[0][r] = *(const float2*)&V0[row];
                    vv[1][r] = *(const float2*)&V1[row];
                    vv[2][r] = *(const float2*)&V2[row];
                }
                #pragma unroll
                for (int n = 0; n < NB; ++n) {
                    #pragma unroll
                    for (int m = 0; m < 9; ++m) {
                        const int lm = (m == 0) ? 0 : ((m < 4) ? 1 : 2);
                        const float4 t4 = *(const float4*)&s_tp[n][m][pb0 + pb];
                        float a = oaA[n][m], b = oaB[n][m];
                        a = fmaf(t4.x, vv[lm][0].x, a);
                        a = fmaf(t4.y, vv[lm][1].x, a);
                        a = fmaf(t4.z, vv[lm][2].x, a);
                        a = fmaf(t4.w, vv[lm][3].x, a);
                        b = fmaf(t4.x, vv[lm][0].y, b);
                        b = fmaf(t4.y, vv[lm][1].y, b);
                        b = fmaf(t4.z, vv[lm][2].y, b);
                        b = fmaf(t4.w, vv[lm][3].y, b);
                        oaA[n][m] = a; oaB[n][m] = b;
                    }
                }
            }
        }
        __syncthreads();

        #pragma unroll
        for (int n = 0; n < NB; ++n) {
            #pragma unroll
            for (int m = 0; m < 9; ++m) {
                float2 t2; t2.x = oaA[n][m]; t2.y = oaB[n][m];
                *(float2*)&s_part[w][n * 9 + m][2 * ln] = t2;
            }
        }
        __syncthreads();

        #pragma unroll
        for (int n = 0; n < NB; ++n)
            #pragma unroll
            for (int m = 0; m < 9; ++m)
                f[n][m] += s_part[0][n * 9 + m][kk] + s_part[1][n * 9 + m][kk];
        __syncthreads();
    }

    #pragma unroll
    for (int n = 0; n < NB; ++n) {
        const int ng = node0 + n;
        #pragma unroll
        for (int m = 0; m < 9; ++m)
            out[(size_t)(ng * 9 + m) * KCH + kk] = f[n][m];
    }
}

extern "C" void kernel_launch(void* const* d_in, const int* in_sizes, int n_in,
                              void* d_out, int out_size, void* d_ws, size_t ws_size,
                              hipStream_t stream) {
    const float* f0    = (const float*)d_in[0];
    const float* f1    = (const float*)d_in[1];
    const float* f2    = (const float*)d_in[2];
    const float* U     = (const float*)d_in[3];
    const float* gamma = (const float*)d_in[4];
    const float* W_in  = (const float*)d_in[5];
    const float* W_out = (const float*)d_in[6];
    float* out = (float*)d_out;

    if (d_ws != nullptr && ws_size >= PACK_BYTES) {
        float* PW = (float*)d_ws;
        float* PV = PW + (size_t)PW_QUADS * 4;
        const int total = PW_QUADS + PV_QUADS;
        dim3 pgrid((total + 255) / 256), pblock(256);
        hipLaunchKernelGGL(pack_weights, pgrid, pblock, 0, stream,
                           W_in, W_out, PW, PV);
        dim3 grid(NNODES / NB), block(NTHR);
        hipLaunchKernelGGL(cg_fused_pk, grid, block, 0, stream,
                           f0, f1, f2, U, gamma, PW, PV, out);
    } else {
        dim3 grid(NNODES / NB), block(NTHR);
        hipLaunchKernelGGL(cg_fused_fb, grid, block, 0, stream,
                           f0, f1, f2, U, gamma, W_in, W_out, out);
    }
}